// Round 3
// baseline (472.380 us; speedup 1.0000x reference)
//
#include <hip/hip_runtime.h>
#include <math.h>

#define HIDDEN 1024

typedef _Float16 half8 __attribute__((ext_vector_type(8)));
typedef float floatx4 __attribute__((ext_vector_type(4)));

// out layout (floats): topk_scores, topk_idx, gate_scores, gate_logits
#define OUT_TKS 0
#define OUT_TKI 147456
#define OUT_GS  294912
#define OUT_GL  5013504

// ws layout: WH = 65536 f16 (128KB) | WL = 65536 f16 (128KB) | QL = 512 f32
// WH/WL are in MFMA B-fragment order: idx = ((c*4+nt)*64 + lane)*8 + j
//   expert e = nt*16 + (lane&15), k = c*32 + (lane>>4)*8 + j
#define QL_FOFF 65536   // float offset of QL (after 65536 f16 *2 arrays = 65536 floats)

// blocks 0..63: split W_vis into f16 hi/lo fragment-ordered arrays
// blocks 64..71: query logits (8 x 64)
__global__ __launch_bounds__(256) void prep_kernel(
    const float* __restrict__ query_emb, const float* __restrict__ W_gate,
    float* __restrict__ ws) {
  const int bid = blockIdx.x, tid = threadIdx.x;
  if (bid < 64) {
    _Float16* WH = (_Float16*)ws;
    _Float16* WL = WH + 65536;
    const int base = (bid * 256 + tid) * 4;
    #pragma unroll
    for (int u = 0; u < 4; ++u) {
      const int idx = base + u;
      const int j  = idx & 7;
      const int L  = (idx >> 3) & 63;
      const int nt = (idx >> 9) & 3;
      const int c  = idx >> 11;
      const int e  = nt * 16 + (L & 15);
      const int k  = c * 32 + (L >> 4) * 8 + j;
      const float w = W_gate[e * 2048 + k];
      const _Float16 hi = (_Float16)w;            // RNE
      const float hif = (float)hi;
      WH[idx] = hi;
      WL[idx] = (_Float16)((w - hif) * 2048.0f);  // scaled: stays normal in f16
    }
  } else {
    const int b = bid - 64;                // 0..7
    const int e = tid >> 2, qq = tid & 3;  // expert, quarter of K
    const float* qp = query_emb + b * 1024 + qq * 256;
    const float* wp = W_gate + e * 2048 + 1024 + qq * 256;
    float s = 0.f;
    #pragma unroll 4
    for (int j = 0; j < 256; j += 4) {
      const float4 a = *(const float4*)(qp + j);
      const float4 w = *(const float4*)(wp + j);
      s += a.x * w.x + a.y * w.y + a.z * w.z + a.w * w.w;
    }
    s += __shfl_xor(s, 1);
    s += __shfl_xor(s, 2);
    if (qq == 0) ws[QL_FOFF + b * 64 + e] = s;
  }
}

// One wave per block; each wave owns 32 tokens x 64 experts (M_rep=2).
// r3: restore B 1-deep register prefetch (r2 had dropped it: every iter
// paid an exposed L2 wait for B) and revert A loads to PLAIN cached loads
// (r2's nontemporal hint plausibly bypassed the L3, where the harness's
// per-iteration input restore leaves ~half of vis resident; round-0
// FETCH_SIZE=152MB for a 302MB stream proves the L3 hits are real).
// NT is kept only on the bulk gs/gl STORES (write-once; keeps L2 clean
// for the shared B fragments).
// Queue discipline per iter i (in-order vmcnt):
//   issue B(c+1) [8 loads] -> issue A(c+1) [4 loads] ->
//   split waits A(c) = vmcnt(12), which also covers the older B(c) ->
//   24 MFMAs run with B(c+1)+A(c+1) (12KB/wave) still in flight.
// fp32 = f16hi + f16lo*2^-11;  A.B = Ah.Bh + 2^-11*(Ah.Bl' + Al'.Bh)
__global__ __launch_bounds__(64, 2) void router_main(
    const float* __restrict__ vis, const float* __restrict__ ws,
    float* __restrict__ out) {
  const int L  = threadIdx.x & 63;  // lane
  const int m  = L & 15;            // A-frag row / C-frag expert col
  const int q  = L >> 4;            // quad
  const long t0 = (long)blockIdx.x * 32;
  const _Float16* WH = (const _Float16*)ws;
  const _Float16* WL = WH + 65536;
  const float* QL = ws + QL_FOFF;

  const float* ab0 = vis + (t0 + m) * HIDDEN + q * 8;        // tokens t0..t0+15
  const float* ab1 = ab0 + 16 * HIDDEN;                       // tokens t0+16..t0+31
  const int fo = L * 8;             // lane offset into fragment arrays (f16 units)

  floatx4 acc[2][4], accx[2][4];
  #pragma unroll
  for (int mf = 0; mf < 2; ++mf)
    #pragma unroll
    for (int nt = 0; nt < 4; ++nt) {
      acc[mf][nt]  = (floatx4){0.f, 0.f, 0.f, 0.f};
      accx[mf][nt] = (floatx4){0.f, 0.f, 0.f, 0.f};
    }

  // ---- prologue: A(0) and B(0) ----
  float4 c00 = *(const float4*)(ab0),     c01 = *(const float4*)(ab0 + 4);
  float4 c10 = *(const float4*)(ab1),     c11 = *(const float4*)(ab1 + 4);
  half8 bh[4], bl[4];
  #pragma unroll
  for (int nt = 0; nt < 4; ++nt) {
    bh[nt] = *(const half8*)(WH + fo + nt * 512);
    bl[nt] = *(const half8*)(WL + fo + nt * 512);
  }

  #pragma unroll 2
  for (int c = 0; c < 32; ++c) {
    const int cn = (c < 31) ? (c + 1) : c;   // tail: reload current, harmless

    // issue B(c+1) FIRST (oldest-consumed-first queue discipline)
    const _Float16* whp = WH + cn * 2048 + fo;
    const _Float16* wlp = WL + cn * 2048 + fo;
    half8 nbh[4], nbl[4];
    #pragma unroll
    for (int nt = 0; nt < 4; ++nt) {
      nbh[nt] = *(const half8*)(whp + nt * 512);
      nbl[nt] = *(const half8*)(wlp + nt * 512);
    }

    // issue A(c+1) (plain cached loads: vis is partly L3-resident)
    const float4 n00 = *(const float4*)(ab0 + cn * 32);
    const float4 n01 = *(const float4*)(ab0 + cn * 32 + 4);
    const float4 n10 = *(const float4*)(ab1 + cn * 32);
    const float4 n11 = *(const float4*)(ab1 + cn * 32 + 4);

    // split current A -> f16 hi + scaled f16 lo (waits A(c): vmcnt(12))
    half8 ah0, al0, ah1, al1;
    {
      const float a0v[8] = {c00.x, c00.y, c00.z, c00.w, c01.x, c01.y, c01.z, c01.w};
      const float a1v[8] = {c10.x, c10.y, c10.z, c10.w, c11.x, c11.y, c11.z, c11.w};
      #pragma unroll
      for (int j = 0; j < 8; ++j) {
        const _Float16 h0 = (_Float16)a0v[j];
        ah0[j] = h0;
        al0[j] = (_Float16)((a0v[j] - (float)h0) * 2048.0f);
        const _Float16 h1 = (_Float16)a1v[j];
        ah1[j] = h1;
        al1[j] = (_Float16)((a1v[j] - (float)h1) * 2048.0f);
      }
    }

    // 24 MFMAs on current B; per-accumulator op order identical to prior rounds
    #pragma unroll
    for (int nt = 0; nt < 4; ++nt) {
      acc[0][nt]  = __builtin_amdgcn_mfma_f32_16x16x32_f16(ah0, bh[nt], acc[0][nt],  0, 0, 0);
      acc[1][nt]  = __builtin_amdgcn_mfma_f32_16x16x32_f16(ah1, bh[nt], acc[1][nt],  0, 0, 0);
      accx[0][nt] = __builtin_amdgcn_mfma_f32_16x16x32_f16(ah0, bl[nt], accx[0][nt], 0, 0, 0);
      accx[1][nt] = __builtin_amdgcn_mfma_f32_16x16x32_f16(ah1, bl[nt], accx[1][nt], 0, 0, 0);
      accx[0][nt] = __builtin_amdgcn_mfma_f32_16x16x32_f16(al0, bh[nt], accx[0][nt], 0, 0, 0);
      accx[1][nt] = __builtin_amdgcn_mfma_f32_16x16x32_f16(al1, bh[nt], accx[1][nt], 0, 0, 0);
    }

    // rotate the pipeline registers
    c00 = n00; c01 = n01; c10 = n10; c11 = n11;
    #pragma unroll
    for (int nt = 0; nt < 4; ++nt) { bh[nt] = nbh[nt]; bl[nt] = nbl[nt]; }
  }

  // ---- epilogue ----
  // C-frag: expert = nt*16 + m, token(frag mf) = t0 + mf*16 + q*4 + reg
  const int bq = blockIdx.x / 288;     // 9216 tokens per query row / 32 per block
  float ql[4];
  #pragma unroll
  for (int nt = 0; nt < 4; ++nt) ql[nt] = QL[bq * 64 + nt * 16 + m];

  float* out_tks = out + OUT_TKS;
  float* out_tki = out + OUT_TKI;
  float* out_gs  = out + OUT_GS;
  float* out_gl  = out + OUT_GL;

  #pragma unroll
  for (int mf = 0; mf < 2; ++mf) {
    #pragma unroll
    for (int i = 0; i < 4; ++i) {
      const long tok = t0 + mf * 16 + q * 4 + i;
      float l[4];
      #pragma unroll
      for (int nt = 0; nt < 4; ++nt)
        l[nt] = acc[mf][nt][i] + accx[mf][nt][i] * (1.0f / 2048.0f) + ql[nt];
      #pragma unroll
      for (int nt = 0; nt < 4; ++nt)
        __builtin_nontemporal_store(l[nt], out_gl + tok * 64 + nt * 16 + m);

      float mx = fmaxf(fmaxf(l[0], l[1]), fmaxf(l[2], l[3]));
      mx = fmaxf(mx, __shfl_xor(mx, 1));
      mx = fmaxf(mx, __shfl_xor(mx, 2));
      mx = fmaxf(mx, __shfl_xor(mx, 4));
      mx = fmaxf(mx, __shfl_xor(mx, 8));

      float s[4], ssum = 0.f;
      #pragma unroll
      for (int nt = 0; nt < 4; ++nt) { s[nt] = expf(l[nt] - mx); ssum += s[nt]; }
      ssum += __shfl_xor(ssum, 1);
      ssum += __shfl_xor(ssum, 2);
      ssum += __shfl_xor(ssum, 4);
      ssum += __shfl_xor(ssum, 8);
      const float inv = 1.0f / ssum;
      #pragma unroll
      for (int nt = 0; nt < 4; ++nt) s[nt] *= inv;
      #pragma unroll
      for (int nt = 0; nt < 4; ++nt)
        __builtin_nontemporal_store(s[nt], out_gs + tok * 64 + nt * 16 + m);

      // local top-2 over the 4 experts this lane owns (ids ascending in nt,
      // strict '>' => lowest index wins ties, jax semantics)
      float v1 = s[0], v2 = s[1]; int i1 = m, i2 = 16 + m;
      if (s[1] > v1) { v2 = v1; i2 = i1; v1 = s[1]; i1 = 16 + m; }
      if (s[2] > v1)      { v2 = v1; i2 = i1; v1 = s[2]; i1 = 32 + m; }
      else if (s[2] > v2) { v2 = s[2]; i2 = 32 + m; }
      if (s[3] > v1)      { v2 = v1; i2 = i1; v1 = s[3]; i1 = 48 + m; }
      else if (s[3] > v2) { v2 = s[3]; i2 = 48 + m; }

      // butterfly merge across the 16-lane group
      #pragma unroll
      for (int msk = 1; msk < 16; msk <<= 1) {
        const float w1 = __shfl_xor(v1, msk), w2 = __shfl_xor(v2, msk);
        const int   j1 = __shfl_xor(i1, msk), j2 = __shfl_xor(i2, msk);
        const bool wfirst = (w1 > v1) || (w1 == v1 && j1 < i1);
        if (wfirst) {
          const bool vsec = (v1 > w2) || (v1 == w2 && i1 < j2);
          v2 = vsec ? v1 : w2; i2 = vsec ? i1 : j2;
          v1 = w1; i1 = j1;
        } else {
          const bool wsec = (w1 > v2) || (w1 == v2 && j1 < i2);
          if (wsec) { v2 = w1; i2 = j1; }
        }
      }
      if (m == 0) {
        *(float2*)(out_tks + tok * 2) = make_float2(v1, v2);
        *(float2*)(out_tki + tok * 2) = make_float2((float)i1, (float)i2);
      }
    }
  }
}

extern "C" void kernel_launch(void* const* d_in, const int* in_sizes, int n_in,
                              void* d_out, int out_size, void* d_ws, size_t ws_size,
                              hipStream_t stream) {
  const float* vis   = (const float*)d_in[0];
  const float* query = (const float*)d_in[1];
  const float* wg    = (const float*)d_in[2];
  float* ws = (float*)d_ws;
  float* o  = (float*)d_out;
  hipLaunchKernelGGL(prep_kernel, dim3(72), dim3(256), 0, stream, query, wg, ws);
  hipLaunchKernelGGL(router_main, dim3(2304), dim3(64), 0, stream, vis, ws, o);
}